// Round 1
// baseline (16256.903 us; speedup 1.0000x reference)
//
#include <hip/hip_runtime.h>
#include <hip/hip_bf16.h>

typedef __hip_bfloat16 bf16;

#define B_ 2
#define Y_ 128
#define X_ 128

struct LevelMeta {
  int S;
  int pi[5], ci[5], ni[5];
  int embmap[9];
};

// ---------------- LayerNorm(+emb) kernel: one wave per row ----------------
template <int CIN>
__global__ __launch_bounds__(64) void ln_kernel(
    const float* __restrict__ in, const float* __restrict__ emb,
    const float* __restrict__ lng, const float* __restrict__ lnb,
    bf16* __restrict__ out, LevelMeta m) {
  int row = blockIdx.x;
  int t = row / (B_ * Y_ * X_);
  int lane = threadIdx.x;
  constexpr int NCH = CIN / 64;
  const float* xr = in + (size_t)row * CIN;
  const float* er = emb + (size_t)m.embmap[t] * CIN;
  float v[NCH];
  float s = 0.f;
#pragma unroll
  for (int k = 0; k < NCH; ++k) {
    int c = lane + (k << 6);
    v[k] = xr[c] + er[c];
    s += v[k];
  }
#pragma unroll
  for (int off = 32; off >= 1; off >>= 1) s += __shfl_xor(s, off);
  float mu = s * (1.0f / CIN);
  float ss = 0.f;
#pragma unroll
  for (int k = 0; k < NCH; ++k) {
    float d = v[k] - mu;
    ss += d * d;
  }
#pragma unroll
  for (int off = 32; off >= 1; off >>= 1) ss += __shfl_xor(ss, off);
  float inv = rsqrtf(ss * (1.0f / CIN) + 1e-3f);
  bf16* orow = out + (size_t)row * CIN;
#pragma unroll
  for (int k = 0; k < NCH; ++k) {
    int c = lane + (k << 6);
    orow[c] = __float2bfloat16((v[k] - mu) * inv * lng[c] + lnb[c]);
  }
}

// ---------------- Fused window attention: one block per (window, image); part given ----------------
// Computes att_part = WindowAttention(q=frame qf, kv=frame kf) @ wo + bo for one 8x8 window.
template <int CIN, int DH>
__global__ __launch_bounds__(256) void attn_kernel(
    const bf16* __restrict__ cur, const float* __restrict__ wqkv,
    const float* __restrict__ bqkv, const float* __restrict__ wo,
    const float* __restrict__ bo, bf16* __restrict__ att, LevelMeta m,
    int part) {
  constexpr int H = CIN / DH;  // 4 heads
  constexpr int NCC = CIN / 4; // channels owned per thread in output accumulation

  __shared__ bf16 sQ[64 * CIN];
  __shared__ bf16 sKV[64 * CIN];
  __shared__ float sP[3 * 64 * DH];  // qp | kp | vp for current head
  __shared__ float sL[64 * 64];      // logits -> attn
  __shared__ float sRed[4][64];

  int wid = blockIdx.x;  // 0..255 windows
  int img = blockIdx.y;  // 0..S*B-1
  int s_ = img / B_, b = img % B_;
  int wy = wid >> 4, wx = wid & 15;
  int qf, kf;
  switch (part) {
    case 0: qf = m.ci[s_]; kf = m.pi[s_]; break;
    case 1: qf = m.pi[s_]; kf = m.ci[s_]; break;
    case 2: qf = m.ci[s_]; kf = m.ni[s_]; break;
    default: qf = m.ni[s_]; kf = m.ci[s_]; break;
  }
  int tid = threadIdx.x;
  int i_tok = tid & 63;
  int grp = tid >> 6;

  const bf16* qbase = cur + ((size_t)(qf * B_ + b) * Y_ * X_) * CIN;
  const bf16* kbase = cur + ((size_t)(kf * B_ + b) * Y_ * X_) * CIN;
  for (int idx = tid; idx < 64 * CIN; idx += 256) {
    int tk = idx / CIN, c = idx % CIN;
    int ty = tk >> 3, tx = tk & 7;
    size_t g = ((size_t)(wy * 8 + ty) * X_ + (wx * 8 + tx)) * CIN + c;
    sQ[idx] = qbase[g];
    sKV[idx] = kbase[g];
  }
  __syncthreads();

  float acc[NCC];
#pragma unroll
  for (int k = 0; k < NCC; ++k) acc[k] = bo[grp * NCC + k];

  float scale = rsqrtf((float)DH);
  float* qp = sP;
  float* kp = sP + 64 * DH;
  float* vp = sP + 2 * 64 * DH;

  for (int h = 0; h < H; ++h) {
    // --- projections for head h: qp/kp/vp [64][DH] ---
    for (int e = tid; e < 3 * 64 * DH; e += 256) {
      int which = e / (64 * DH);
      int rem = e % (64 * DH);
      int tk = rem / DH, d = rem % DH;
      int col = h * DH + d;
      const bf16* src = (which == 0) ? (sQ + tk * CIN) : (sKV + tk * CIN);
      const float* w = wqkv + (size_t)which * CIN * CIN + col;
      float sum = bqkv[which * CIN + col];
      for (int c = 0; c < CIN; ++c)
        sum += __bfloat162float(src[c]) * w[(size_t)c * CIN];
      sP[e] = sum;
    }
    __syncthreads();

    // --- logits: thread covers (i_tok, j in [grp*16, grp*16+16)) ---
    for (int j = grp * 16; j < grp * 16 + 16; ++j) {
      float l = 0.f;
      for (int d = 0; d < DH; ++d) l += qp[i_tok * DH + d] * kp[j * DH + d];
      sL[i_tok * 64 + j] = l * scale;
    }
    // --- softmax over j (row i_tok): cross-group reduce via LDS ---
    float mx = -1e30f;
    for (int j = grp * 16; j < grp * 16 + 16; ++j)
      mx = fmaxf(mx, sL[i_tok * 64 + j]);
    __syncthreads();
    sRed[grp][i_tok] = mx;
    __syncthreads();
    mx = fmaxf(fmaxf(sRed[0][i_tok], sRed[1][i_tok]),
               fmaxf(sRed[2][i_tok], sRed[3][i_tok]));
    float ps = 0.f;
    for (int j = grp * 16; j < grp * 16 + 16; ++j) {
      float ev = __expf(sL[i_tok * 64 + j] - mx);
      sL[i_tok * 64 + j] = ev;
      ps += ev;
    }
    __syncthreads();
    sRed[grp][i_tok] = ps;
    __syncthreads();
    float inv = 1.0f / (sRed[0][i_tok] + sRed[1][i_tok] + sRed[2][i_tok] +
                        sRed[3][i_tok]);
    for (int j = grp * 16; j < grp * 16 + 16; ++j) sL[i_tok * 64 + j] *= inv;
    __syncthreads();

    // --- out_h = attn @ vp  [64][DH], stored into qp region (free now) ---
    for (int e2 = tid; e2 < 64 * DH; e2 += 256) {
      int tk = e2 / DH, d = e2 % DH;
      float sum = 0.f;
      for (int j = 0; j < 64; ++j) sum += sL[tk * 64 + j] * vp[j * DH + d];
      qp[e2] = sum;
    }
    __syncthreads();

    // --- accumulate out_h @ wo rows into per-thread acc ---
    for (int d = 0; d < DH; ++d) {
      float o = qp[i_tok * DH + d];
      const float* worow = wo + (size_t)(h * DH + d) * CIN + grp * NCC;
#pragma unroll
      for (int k = 0; k < NCC; ++k) acc[k] += o * worow[k];
    }
    __syncthreads();  // before next head overwrites sP
  }

  // --- write att (bf16), token (i_tok), channels [grp*NCC, grp*NCC+NCC) ---
  {
    int ty = i_tok >> 3, tx = i_tok & 7;
    size_t row = ((size_t)img * Y_ + (wy * 8 + ty)) * X_ + (wx * 8 + tx);
    bf16* dst = att + row * CIN + grp * NCC;
#pragma unroll
    for (int k = 0; k < NCC; ++k) dst[k] = __float2bfloat16(acc[k]);
  }
}

// ---------------- down conv: accum += att_part @ cw[part]; relu on last part ----------------
template <int CIN, int CO>
__global__ __launch_bounds__(256) void down_kernel(
    const bf16* __restrict__ att, const float* __restrict__ cw,
    const float* __restrict__ cb, float* __restrict__ accum, int part) {
  __shared__ bf16 sA[64 * CIN];
  constexpr int NCO = CO / 4;
  int tid = threadIdx.x;
  size_t t0 = (size_t)blockIdx.x * 64;
  for (int idx = tid; idx < 64 * CIN; idx += 256)
    sA[idx] = att[t0 * CIN + idx];
  __syncthreads();
  int i = tid & 63, grp = tid >> 6;
  float acc[NCO];
  const float* cwp = cw + (size_t)part * CIN * CO + grp * NCO;
  if (part == 0) {
#pragma unroll
    for (int k = 0; k < NCO; ++k) acc[k] = cb[grp * NCO + k];
  } else {
    const float* arow = accum + (t0 + i) * CO + grp * NCO;
#pragma unroll
    for (int k = 0; k < NCO; ++k) acc[k] = arow[k];
  }
  for (int c = 0; c < CIN; ++c) {
    float v = __bfloat162float(sA[i * CIN + c]);
    const float* wr = cwp + (size_t)c * CO;
#pragma unroll
    for (int k = 0; k < NCO; ++k) acc[k] += v * wr[k];
  }
  float* orow = accum + (t0 + i) * CO + grp * NCO;
  if (part == 3) {
#pragma unroll
    for (int k = 0; k < NCO; ++k) orow[k] = fmaxf(acc[k], 0.f);
  } else {
#pragma unroll
    for (int k = 0; k < NCO; ++k) orow[k] = acc[k];
  }
}

extern "C" void kernel_launch(void* const* d_in, const int* in_sizes, int n_in,
                              void* d_out, int out_size, void* d_ws,
                              size_t ws_size, hipStream_t stream) {
  const float* x = (const float*)d_in[0];
#define P(l, k) ((const float*)d_in[1 + 9 * (l) + (k)])
  float* out = (float*)d_out;
  float* outCur = out;                      // [2,128,128,256] final level
  float* outL1 = out + (size_t)8388608;     // [5,2,128,128,128] level-0 down

  // workspace: cur (bf16, max 20.97M elems), att (bf16, max 12.58M elems),
  // accum for level-1 down (fp32, 6*16384*192)
  bf16* cur = (bf16*)d_ws;
  bf16* att = (bf16*)((char*)d_ws + 41943040ull);
  float* accum1 = (float*)((char*)d_ws + 41943040ull + 25165824ull);

  LevelMeta m0 = {5,
                  {0, 1, 3, 5, 6},
                  {1, 2, 4, 6, 7},
                  {2, 3, 5, 7, 8},
                  {0, 1, 2, 3, 4, 5, 6, 7, 8}};
  LevelMeta m1 = {3,
                  {0, 1, 2, 0, 0},
                  {1, 2, 3, 0, 0},
                  {2, 3, 4, 0, 0},
                  {1, 2, 4, 6, 7, 0, 0, 0, 0}};
  LevelMeta m2 = {1,
                  {0, 0, 0, 0, 0},
                  {1, 0, 0, 0, 0},
                  {2, 0, 0, 0, 0},
                  {2, 4, 6, 0, 0, 0, 0, 0, 0}};

  // ---- Level 0: cin=64, co=128, dh=16, Tl=9, S=5 ----
  ln_kernel<64><<<dim3(9 * B_ * Y_ * X_ / 1), 64, 0, stream>>>(
      x, P(0, 0), P(0, 1), P(0, 2), cur, m0);
  for (int p = 0; p < 4; ++p) {
    attn_kernel<64, 16><<<dim3(256, 5 * B_), 256, 0, stream>>>(
        cur, P(0, 3), P(0, 4), P(0, 5), P(0, 6), att, m0, p);
    down_kernel<64, 128><<<dim3(5 * B_ * Y_ * X_ / 64), 256, 0, stream>>>(
        att, P(0, 7), P(0, 8), outL1, p);
  }

  // ---- Level 1: cin=128, co=192, dh=32, Tl=5, S=3 ----
  ln_kernel<128><<<dim3(5 * B_ * Y_ * X_), 64, 0, stream>>>(
      outL1, P(1, 0), P(1, 1), P(1, 2), cur, m1);
  for (int p = 0; p < 4; ++p) {
    attn_kernel<128, 32><<<dim3(256, 3 * B_), 256, 0, stream>>>(
        cur, P(1, 3), P(1, 4), P(1, 5), P(1, 6), att, m1, p);
    down_kernel<128, 192><<<dim3(3 * B_ * Y_ * X_ / 64), 256, 0, stream>>>(
        att, P(1, 7), P(1, 8), accum1, p);
  }

  // ---- Level 2: cin=192, co=256, dh=48, Tl=3, S=1 ----
  ln_kernel<192><<<dim3(3 * B_ * Y_ * X_), 64, 0, stream>>>(
      accum1, P(2, 0), P(2, 1), P(2, 2), cur, m2);
  for (int p = 0; p < 4; ++p) {
    attn_kernel<192, 48><<<dim3(256, 1 * B_), 256, 0, stream>>>(
        cur, P(2, 3), P(2, 4), P(2, 5), P(2, 6), att, m2, p);
    down_kernel<192, 256><<<dim3(1 * B_ * Y_ * X_ / 64), 256, 0, stream>>>(
        att, P(2, 7), P(2, 8), outCur, p);
  }
#undef P
}

// Round 2
// 1367.556 us; speedup vs baseline: 11.8876x; 11.8876x over previous
//
#include <hip/hip_runtime.h>

typedef _Float16 f16;
typedef f16 f16x4 __attribute__((ext_vector_type(4)));
typedef f16 f16x8 __attribute__((ext_vector_type(8)));
typedef float f32x4 __attribute__((ext_vector_type(4)));

#define MFMA16(a, b, c) __builtin_amdgcn_mfma_f32_16x16x16f16((a), (b), (c), 0, 0, 0)
#define MFMA32(a, b, c) __builtin_amdgcn_mfma_f32_16x16x32_f16((a), (b), (c), 0, 0, 0)

struct Meta   { int qf[5]; int kf[5]; };
struct EmbMap { int m[9]; };

// ---------------- LayerNorm(+temporal emb) -> f16 ----------------
// One wave per row. May run in-place (fp32 in, f16 out over same rows): all
// loads complete (data dep through mu/var) before any store.
template <int CIN>
__global__ __launch_bounds__(64) void ln_kernel(
    const float* in, long lda, const float* __restrict__ emb,
    const float* __restrict__ lng, const float* __restrict__ lnb,
    f16* out, long ldo, EmbMap em) {
  long row = blockIdx.x;
  int t = (int)(row >> 15);  // B*Y*X = 32768
  int lane = threadIdx.x;
  constexpr int NCH = CIN / 64;
  const float* xr = in + row * lda;
  const float* er = emb + (long)em.m[t] * CIN;
  float v[NCH];
  float s = 0.f;
#pragma unroll
  for (int i = 0; i < NCH; ++i) { int c = lane + (i << 6); v[i] = xr[c] + er[c]; s += v[i]; }
#pragma unroll
  for (int o = 32; o >= 1; o >>= 1) s += __shfl_xor(s, o);
  float mu = s * (1.f / CIN), ss = 0.f;
#pragma unroll
  for (int i = 0; i < NCH; ++i) { float d = v[i] - mu; ss += d * d; }
#pragma unroll
  for (int o = 32; o >= 1; o >>= 1) ss += __shfl_xor(ss, o);
  float inv = rsqrtf(ss * (1.f / CIN) + 1e-3f);
  f16* orow = out + row * ldo;
#pragma unroll
  for (int i = 0; i < NCH; ++i) {
    int c = lane + (i << 6);
    orow[c] = (f16)((v[i] - mu) * inv * lng[c] + lnb[c]);
  }
}

// ---------------- wqkv transpose+convert: wqkvT[j][c] = wqkv[which][c][jj] ----
template <int CIN>
__global__ __launch_bounds__(64) void wT_kernel(const float* __restrict__ wqkv,
                                                f16* __restrict__ wqkvT) {
  int j = blockIdx.x;  // 0..3CIN-1
  int which = j / CIN, jj = j % CIN;
  const float* src = wqkv + (long)which * CIN * CIN + jj;
  f16* dst = wqkvT + (long)j * CIN;
  for (int c = threadIdx.x; c < CIN; c += 64) dst[c] = (f16)src[(long)c * CIN];
}

// ---------------- fused out-proj weights: wocT[o][p*CIN+m] = sum_c wo[m][c]*cw[p*CIN+c][o]
// fb[o] = cb[o] + sum_{p,c} bo[c]*cw[p*CIN+c][o]
template <int CIN, int CO>
__global__ __launch_bounds__(256) void woc_kernel(
    const float* __restrict__ wo, const float* __restrict__ bo,
    const float* __restrict__ cw, const float* __restrict__ cb,
    f16* __restrict__ wocT, float* __restrict__ fb) {
  __shared__ float scw[4 * CIN];
  __shared__ float red[256];
  int o = blockIdx.x;
  for (int i = threadIdx.x; i < 4 * CIN; i += 256) scw[i] = cw[(long)i * CO + o];
  __syncthreads();
  for (int pm = threadIdx.x; pm < 4 * CIN; pm += 256) {
    int p = pm / CIN, mm = pm % CIN;
    const float* wr = wo + (long)mm * CIN;
    const float* sc = scw + p * CIN;
    float s = 0.f;
    for (int c = 0; c < CIN; ++c) s += wr[c] * sc[c];
    wocT[(long)o * 4 * CIN + pm] = (f16)s;
  }
  float part = 0.f;
  for (int i = threadIdx.x; i < 4 * CIN; i += 256) part += bo[i % CIN] * scw[i];
  red[threadIdx.x] = part;
  __syncthreads();
  for (int st = 128; st > 0; st >>= 1) {
    if (threadIdx.x < st) red[threadIdx.x] += red[threadIdx.x + st];
    __syncthreads();
  }
  if (threadIdx.x == 0) fb[o] = cb[o] + red[0];
}

// ---------------- QKV projection GEMM (MFMA 16x16x32 f16) ----------------
// out[tok][j] = sum_c cur[tok][c]*wqkvT[j][c] + bqkv[j];  j<CIN -> q, <2CIN -> k,
// else v transposed: vt[(img*CIN + c)*16384 + loc].
template <int CIN>
__global__ __launch_bounds__(256) void proj_kernel(
    const f16* __restrict__ cur, long lda, const f16* __restrict__ wT,
    const float* __restrict__ bqkv, f16* __restrict__ gq, f16* __restrict__ gk,
    f16* __restrict__ gvt) {
  constexpr int KSTEPS = CIN / 32;
  int lane = threadIdx.x & 63, w = threadIdx.x >> 6;
  int r16 = lane & 15, kq = lane >> 4;
  long R = (long)blockIdx.y * 64 + w * 16;
  int Cb = blockIdx.x * 64;
  const f16* arow = cur + (R + r16) * lda + kq * 8;
  const f16* bbase = wT + (long)(Cb + r16) * CIN + kq * 8;
  f32x4 acc[4] = {};
#pragma unroll
  for (int ks = 0; ks < KSTEPS; ++ks) {
    f16x8 a = *(const f16x8*)(arow + ks * 32);
#pragma unroll
    for (int t = 0; t < 4; ++t) {
      f16x8 bb = *(const f16x8*)(bbase + (long)t * 16 * CIN + ks * 32);
      acc[t] = MFMA32(a, bb, acc[t]);
    }
  }
  long tok0 = R + kq * 4;
#pragma unroll
  for (int t = 0; t < 4; ++t) {
    int j = Cb + t * 16 + r16;
    float bias = bqkv[j];
    if (j < CIN) {
#pragma unroll
      for (int rg = 0; rg < 4; ++rg) gq[(tok0 + rg) * CIN + j] = (f16)(acc[t][rg] + bias);
    } else if (j < 2 * CIN) {
      int jj = j - CIN;
#pragma unroll
      for (int rg = 0; rg < 4; ++rg) gk[(tok0 + rg) * CIN + jj] = (f16)(acc[t][rg] + bias);
    } else {
      int c = j - 2 * CIN;
      long img = tok0 >> 14, loc = tok0 & 16383;
      f16x4 pk;
#pragma unroll
      for (int rg = 0; rg < 4; ++rg) pk[rg] = (f16)(acc[t][rg] + bias);
      *(f16x4*)(gvt + (img * CIN + c) * 16384 + loc) = pk;
    }
  }
}

// ---------------- fused window attention + down-conv accumulate ----------------
// Block = one 8x8 window of one (s,b) image, one part. Wave = head.
template <int CIN, int DH, int CO>
__global__ __launch_bounds__(256) void attn_kernel(
    const f16* __restrict__ gq, const f16* __restrict__ gk,
    const f16* __restrict__ gvt, const f16* __restrict__ wocT,
    const float* __restrict__ fb, float* accum, int part, Meta m) {
  constexpr int NKS = DH / 16;   // score k-steps / PV d-tiles
  constexpr int CO4 = CO / 4;
  constexpr int NTC = CO4 / 16;  // down col-tiles per wave
  constexpr int NKD = CIN / 32;  // down k-steps
  constexpr float scale = (DH == 16) ? 0.25f : (DH == 32) ? 0.1767766952966369f
                                                          : 0.1443375672974064f;
  __shared__ f16 P[4 * 64 * 64];
  __shared__ f16 O[64 * CIN];

  int img = blockIdx.y;
  int sidx = img >> 1, b = img & 1;
  int wy = blockIdx.x >> 4, wx = blockIdx.x & 15;
  int h = threadIdx.x >> 6, lane = threadIdx.x & 63;
  int r16 = lane & 15, kq = lane >> 4;

  int kimg = m.kf[sidx] * 2 + b;
  long qbase = (long)(m.qf[sidx] * 2 + b) * 16384;
  long kbase = (long)kimg * 16384;

  int wt[4];
#pragma unroll
  for (int t = 0; t < 4; ++t) {
    int i = t * 16 + r16;
    wt[t] = (wy * 8 + (i >> 3)) * 128 + wx * 8 + (i & 7);
  }

  // ---- scores (wave = head h) ----
  f32x4 sc[4][4] = {};
#pragma unroll
  for (int ks = 0; ks < NKS; ++ks) {
    int koff = h * DH + ks * 16 + kq * 4;
    f16x4 af[4], bf[4];
#pragma unroll
    for (int t = 0; t < 4; ++t) {
      af[t] = *(const f16x4*)(gq + (qbase + wt[t]) * CIN + koff);
      bf[t] = *(const f16x4*)(gk + (kbase + wt[t]) * CIN + koff);
    }
#pragma unroll
    for (int ti = 0; ti < 4; ++ti)
#pragma unroll
      for (int tj = 0; tj < 4; ++tj) sc[ti][tj] = MFMA16(af[ti], bf[tj], sc[ti][tj]);
  }

  // ---- softmax over j; write P (f16, xor-swizzled) ----
#pragma unroll
  for (int ti = 0; ti < 4; ++ti) {
#pragma unroll
    for (int rg = 0; rg < 4; ++rg) {
      float mx = fmaxf(fmaxf(sc[ti][0][rg], sc[ti][1][rg]),
                       fmaxf(sc[ti][2][rg], sc[ti][3][rg]));
      mx = fmaxf(mx, __shfl_xor(mx, 1));
      mx = fmaxf(mx, __shfl_xor(mx, 2));
      mx = fmaxf(mx, __shfl_xor(mx, 4));
      mx = fmaxf(mx, __shfl_xor(mx, 8));
      float sum = 0.f;
#pragma unroll
      for (int tj = 0; tj < 4; ++tj) {
        float e = __expf((sc[ti][tj][rg] - mx) * scale);
        sc[ti][tj][rg] = e;
        sum += e;
      }
      sum += __shfl_xor(sum, 1);
      sum += __shfl_xor(sum, 2);
      sum += __shfl_xor(sum, 4);
      sum += __shfl_xor(sum, 8);
      float inv = 1.f / sum;
      int i = ti * 16 + kq * 4 + rg;
      int swz = (i & 7) << 3;
#pragma unroll
      for (int tj = 0; tj < 4; ++tj) {
        int off = ((h * 4096 + i * 64 + tj * 16 + r16) * 2) ^ swz;
        *(f16*)((char*)P + off) = (f16)(sc[ti][tj][rg] * inv);
      }
    }
  }
  __syncthreads();

  // ---- PV: out_h[64][DH] ----
  f32x4 po[4][NKS] = {};
#pragma unroll
  for (int ksj = 0; ksj < 4; ++ksj) {
    f16x4 pa[4];
#pragma unroll
    for (int ti = 0; ti < 4; ++ti) {
      int i = ti * 16 + r16;
      int off = ((h * 4096 + i * 64 + ksj * 16 + kq * 4) * 2) ^ ((i & 7) << 3);
      pa[ti] = *(const f16x4*)((char*)P + off);
    }
    int jj = ksj * 16 + kq * 4;
    long vloc = (wy * 8 + (jj >> 3)) * 128 + wx * 8 + (jj & 7);
#pragma unroll
    for (int td = 0; td < NKS; ++td) {
      int d = h * DH + td * 16 + r16;
      f16x4 bv = *(const f16x4*)(gvt + ((long)kimg * CIN + d) * 16384 + vloc);
#pragma unroll
      for (int ti = 0; ti < 4; ++ti) po[ti][td] = MFMA16(pa[ti], bv, po[ti][td]);
    }
  }
  // write O (f16, xor-swizzled for 16B reads)
#pragma unroll
  for (int ti = 0; ti < 4; ++ti)
#pragma unroll
    for (int td = 0; td < NKS; ++td)
#pragma unroll
      for (int rg = 0; rg < 4; ++rg) {
        int i = ti * 16 + kq * 4 + rg;
        int c = h * DH + td * 16 + r16;
        int off = ((i * CIN + c) * 2) ^ ((i & 7) << 4);
        *(f16*)((char*)O + off) = (f16)po[ti][td][rg];
      }
  __syncthreads();

  // ---- down: dn[64][CO] += O @ woc_part; RMW accumulate ----
  f32x4 dn[4][NTC] = {};
#pragma unroll
  for (int ks = 0; ks < NKD; ++ks) {
    f16x8 oa[4];
#pragma unroll
    for (int ti = 0; ti < 4; ++ti) {
      int i = ti * 16 + r16;
      int off = ((i * CIN + ks * 32 + kq * 8) * 2) ^ ((i & 7) << 4);
      oa[ti] = *(const f16x8*)((char*)O + off);
    }
#pragma unroll
    for (int tc = 0; tc < NTC; ++tc) {
      int o = h * CO4 + tc * 16 + r16;
      f16x8 bw = *(const f16x8*)(wocT + ((long)o * 4 + part) * CIN + ks * 32 + kq * 8);
#pragma unroll
      for (int ti = 0; ti < 4; ++ti) dn[ti][tc] = MFMA32(oa[ti], bw, dn[ti][tc]);
    }
  }
#pragma unroll
  for (int ti = 0; ti < 4; ++ti)
#pragma unroll
    for (int rg = 0; rg < 4; ++rg) {
      int i = ti * 16 + kq * 4 + rg;
      long gtok = (long)img * 16384 + (wy * 8 + (i >> 3)) * 128 + wx * 8 + (i & 7);
      float* ar = accum + gtok * CO + h * CO4;
#pragma unroll
      for (int tc = 0; tc < NTC; ++tc) {
        int o = tc * 16 + r16;
        float val = dn[ti][tc][rg];
        if (part == 0) val += fb[h * CO4 + o];
        else           val += ar[o];
        if (part == 3) val = fmaxf(val, 0.f);
        ar[o] = val;
      }
    }
}

extern "C" void kernel_launch(void* const* d_in, const int* in_sizes, int n_in,
                              void* d_out, int out_size, void* d_ws, size_t ws_size,
                              hipStream_t stream) {
  const float* x = (const float*)d_in[0];
#define PRM(l, k) ((const float*)d_in[1 + 9 * (l) + (k)])
  float* outCur = (float*)d_out;                 // [2,128,128,256]
  float* outL1 = (float*)d_out + 8388608;        // [5,2,128,128,128]

  char* ws = (char*)d_ws;
  const size_t OFF_B = 125829120ull;             // qkv arena (max 126 MB @ L1)
  const size_t OFF_W = OFF_B + 75497472ull;      // cur / accum1 arena (75.5 MB)
  f16* qkvbase = (f16*)ws;
  char* wsB = ws + OFF_B;
  float* accum1 = (float*)wsB;
  f16* wqkvT = (f16*)(ws + OFF_W);
  f16* wocT = (f16*)(ws + OFF_W + 262144);
  float* fb = (float*)(ws + OFF_W + 262144 + 524288);

  static const int pi0[5] = {0, 1, 3, 5, 6}, ci0[5] = {1, 2, 4, 6, 7}, ni0[5] = {2, 3, 5, 7, 8};
  static const int pi1[3] = {0, 1, 2}, ci1[3] = {1, 2, 3}, ni1[3] = {2, 3, 4};
  static const int pi2[1] = {0}, ci2[1] = {1}, ni2[1] = {2};
  EmbMap em0 = {{0, 1, 2, 3, 4, 5, 6, 7, 8}};
  EmbMap em1 = {{1, 2, 4, 6, 7, 0, 0, 0, 0}};
  EmbMap em2 = {{2, 4, 6, 0, 0, 0, 0, 0, 0}};
  auto mkMeta = [](const int* a, const int* bb, int S) {
    Meta mm{};
    for (int i = 0; i < S; ++i) { mm.qf[i] = a[i]; mm.kf[i] = bb[i]; }
    return mm;
  };

  // ---------------- Level 0: CIN=64, DH=16, CO=128, TL=9, S=5 ----------------
  {
    constexpr int CIN = 64, DH = 16, CO = 128, TL = 9, S = 5;
    long ntok = (long)TL * 2 * 16384;
    f16 *gq = qkvbase, *gk = gq + ntok * CIN, *gvt = gk + ntok * CIN;
    f16* cur = (f16*)wsB;
    ln_kernel<CIN><<<dim3((unsigned)ntok), 64, 0, stream>>>(
        x, CIN, PRM(0, 0), PRM(0, 1), PRM(0, 2), cur, CIN, em0);
    wT_kernel<CIN><<<dim3(3 * CIN), 64, 0, stream>>>(PRM(0, 3), wqkvT);
    woc_kernel<CIN, CO><<<dim3(CO), 256, 0, stream>>>(PRM(0, 5), PRM(0, 6), PRM(0, 7), PRM(0, 8), wocT, fb);
    proj_kernel<CIN><<<dim3(3 * CIN / 64, (unsigned)(ntok / 64)), 256, 0, stream>>>(
        cur, CIN, wqkvT, PRM(0, 4), gq, gk, gvt);
    Meta mp[4] = {mkMeta(ci0, pi0, S), mkMeta(pi0, ci0, S), mkMeta(ci0, ni0, S), mkMeta(ni0, ci0, S)};
    for (int p = 0; p < 4; ++p)
      attn_kernel<CIN, DH, CO><<<dim3(256, S * 2), 256, 0, stream>>>(
          gq, gk, gvt, wocT, fb, outL1, p, mp[p]);
  }
  // ---------------- Level 1: CIN=128, DH=32, CO=192, TL=5, S=3 ----------------
  {
    constexpr int CIN = 128, DH = 32, CO = 192, TL = 5, S = 3;
    long ntok = (long)TL * 2 * 16384;
    f16 *gq = qkvbase, *gk = gq + ntok * CIN, *gvt = gk + ntok * CIN;
    f16* cur = (f16*)wsB;
    ln_kernel<CIN><<<dim3((unsigned)ntok), 64, 0, stream>>>(
        outL1, CIN, PRM(1, 0), PRM(1, 1), PRM(1, 2), cur, CIN, em1);
    wT_kernel<CIN><<<dim3(3 * CIN), 64, 0, stream>>>(PRM(1, 3), wqkvT);
    woc_kernel<CIN, CO><<<dim3(CO), 256, 0, stream>>>(PRM(1, 5), PRM(1, 6), PRM(1, 7), PRM(1, 8), wocT, fb);
    proj_kernel<CIN><<<dim3(3 * CIN / 64, (unsigned)(ntok / 64)), 256, 0, stream>>>(
        cur, CIN, wqkvT, PRM(1, 4), gq, gk, gvt);
    Meta mp[4] = {mkMeta(ci1, pi1, S), mkMeta(pi1, ci1, S), mkMeta(ci1, ni1, S), mkMeta(ni1, ci1, S)};
    for (int p = 0; p < 4; ++p)
      attn_kernel<CIN, DH, CO><<<dim3(256, S * 2), 256, 0, stream>>>(
          gq, gk, gvt, wocT, fb, accum1, p, mp[p]);
  }
  // ---------------- Level 2: CIN=192, DH=48, CO=256, TL=3, S=1 ----------------
  {
    constexpr int CIN = 192, DH = 48, CO = 256, TL = 3, S = 1;
    long ntok = (long)TL * 2 * 16384;
    f16 *gq = qkvbase, *gk = gq + ntok * CIN, *gvt = gk + ntok * CIN;
    // LN in-place over accum1: fp32 rows (stride 192) -> f16 rows (stride 384)
    f16* cur = (f16*)accum1;
    ln_kernel<CIN><<<dim3((unsigned)ntok), 64, 0, stream>>>(
        accum1, CIN, PRM(2, 0), PRM(2, 1), PRM(2, 2), cur, 384, em2);
    wT_kernel<CIN><<<dim3(3 * CIN), 64, 0, stream>>>(PRM(2, 3), wqkvT);
    woc_kernel<CIN, CO><<<dim3(CO), 256, 0, stream>>>(PRM(2, 5), PRM(2, 6), PRM(2, 7), PRM(2, 8), wocT, fb);
    proj_kernel<CIN><<<dim3(3 * CIN / 64, (unsigned)(ntok / 64)), 256, 0, stream>>>(
        cur, 384, wqkvT, PRM(2, 4), gq, gk, gvt);
    Meta mp[4] = {mkMeta(ci2, pi2, S), mkMeta(pi2, ci2, S), mkMeta(ci2, ni2, S), mkMeta(ni2, ci2, S)};
    for (int p = 0; p < 4; ++p)
      attn_kernel<CIN, DH, CO><<<dim3(256, S * 2), 256, 0, stream>>>(
          gq, gk, gvt, wocT, fb, outCur, p, mp[p]);
  }
#undef PRM
}

// Round 3
// 1298.237 us; speedup vs baseline: 12.5223x; 1.0534x over previous
//
#include <hip/hip_runtime.h>

typedef _Float16 f16;
typedef f16 f16x4 __attribute__((ext_vector_type(4)));
typedef f16 f16x8 __attribute__((ext_vector_type(8)));
typedef float f32x4 __attribute__((ext_vector_type(4)));

#define MFMA16(a, b, c) __builtin_amdgcn_mfma_f32_16x16x16f16((a), (b), (c), 0, 0, 0)
#define MFMA32(a, b, c) __builtin_amdgcn_mfma_f32_16x16x32_f16((a), (b), (c), 0, 0, 0)

struct Meta   { int pi[5], ci[5], ni[5]; };
struct EmbMap { int m[9]; };

// ---------------- LayerNorm(+temporal emb) -> f16, 4 rows/block ----------------
template <int CIN>
__global__ __launch_bounds__(256) void ln_kernel(
    const float* in, long lda, const float* __restrict__ emb,
    const float* __restrict__ lng, const float* __restrict__ lnb,
    f16* out, long ldo, EmbMap em) {
  long row = (long)blockIdx.x * 4 + (threadIdx.x >> 6);
  int t = (int)(row >> 15);  // B*Y*X = 32768
  int lane = threadIdx.x & 63;
  constexpr int NCH = CIN / 64;
  const float* xr = in + row * lda;
  const float* er = emb + (long)em.m[t] * CIN;
  float v[NCH];
  float s = 0.f;
#pragma unroll
  for (int i = 0; i < NCH; ++i) { int c = lane + (i << 6); v[i] = xr[c] + er[c]; s += v[i]; }
#pragma unroll
  for (int o = 32; o >= 1; o >>= 1) s += __shfl_xor(s, o);
  float mu = s * (1.f / CIN), ss = 0.f;
#pragma unroll
  for (int i = 0; i < NCH; ++i) { float d = v[i] - mu; ss += d * d; }
#pragma unroll
  for (int o = 32; o >= 1; o >>= 1) ss += __shfl_xor(ss, o);
  float inv = rsqrtf(ss * (1.f / CIN) + 1e-3f);
  f16* orow = out + row * ldo;
#pragma unroll
  for (int i = 0; i < NCH; ++i) {
    int c = lane + (i << 6);
    orow[c] = (f16)((v[i] - mu) * inv * lng[c] + lnb[c]);
  }
}

// ---------------- wqkv transpose+convert: wqkvT[j][c] = wqkv[which][c][jj] ----
template <int CIN>
__global__ __launch_bounds__(64) void wT_kernel(const float* __restrict__ wqkv,
                                                f16* __restrict__ wqkvT) {
  int j = blockIdx.x;
  int which = j / CIN, jj = j % CIN;
  const float* src = wqkv + (long)which * CIN * CIN + jj;
  f16* dst = wqkvT + (long)j * CIN;
  for (int c = threadIdx.x; c < CIN; c += 64) dst[c] = (f16)src[(long)c * CIN];
}

// ---------------- fused out-proj weights ----------------
template <int CIN, int CO>
__global__ __launch_bounds__(256) void woc_kernel(
    const float* __restrict__ wo, const float* __restrict__ bo,
    const float* __restrict__ cw, const float* __restrict__ cb,
    f16* __restrict__ wocT, float* __restrict__ fb) {
  __shared__ float scw[4 * CIN];
  __shared__ float red[256];
  int o = blockIdx.x;
  for (int i = threadIdx.x; i < 4 * CIN; i += 256) scw[i] = cw[(long)i * CO + o];
  __syncthreads();
  for (int pm = threadIdx.x; pm < 4 * CIN; pm += 256) {
    int p = pm / CIN, mm = pm % CIN;
    const float* wr = wo + (long)mm * CIN;
    const float* sc = scw + p * CIN;
    float s = 0.f;
    for (int c = 0; c < CIN; ++c) s += wr[c] * sc[c];
    wocT[(long)o * 4 * CIN + pm] = (f16)s;
  }
  float part = 0.f;
  for (int i = threadIdx.x; i < 4 * CIN; i += 256) part += bo[i % CIN] * scw[i];
  red[threadIdx.x] = part;
  __syncthreads();
  for (int st = 128; st > 0; st >>= 1) {
    if (threadIdx.x < st) red[threadIdx.x] += red[threadIdx.x + st];
    __syncthreads();
  }
  if (threadIdx.x == 0) fb[o] = cb[o] + red[0];
}

// ---------------- QKV projection GEMM, LDS-staged coalesced stores ----------------
// grid = (3, ntok/64); blockIdx.x = which (0=q,1=k,2=v). Block: 64 toks x CIN cols.
template <int CIN>
__global__ __launch_bounds__(256) void proj_kernel(
    const f16* __restrict__ cur, long lda, const f16* __restrict__ wT,
    const float* __restrict__ bqkv, f16* __restrict__ gq, f16* __restrict__ gk,
    f16* __restrict__ gvt) {
  constexpr int KS = CIN / 32;
  constexpr int NT = CIN / 16;
  constexpr int C8 = CIN / 8;
  __shared__ f16 sO[64 * CIN];
  int which = blockIdx.x;
  long R = (long)blockIdx.y * 64;
  int w = threadIdx.x >> 6, lane = threadIdx.x & 63;
  int r16 = lane & 15, kq = lane >> 4;
  const f16* arow = cur + (R + w * 16 + r16) * lda + kq * 8;
  const f16* bbase = wT + ((long)which * CIN + r16) * CIN + kq * 8;
  f32x4 acc[NT] = {};
#pragma unroll
  for (int ks = 0; ks < KS; ++ks) {
    f16x8 a = *(const f16x8*)(arow + ks * 32);
#pragma unroll
    for (int t = 0; t < NT; ++t) {
      f16x8 bb = *(const f16x8*)(bbase + t * 16 * CIN + ks * 32);
      acc[t] = MFMA32(a, bb, acc[t]);
    }
  }
  // stage to LDS (XOR-swizzled rows) with bias
#pragma unroll
  for (int t = 0; t < NT; ++t) {
    float bias = bqkv[which * CIN + t * 16 + r16];
#pragma unroll
    for (int rg = 0; rg < 4; ++rg) {
      int r = w * 16 + kq * 4 + rg;
      int c = t * 16 + r16;
      int off = ((r * CIN + c) * 2) ^ ((r & 7) << 4);
      *(f16*)((char*)sO + off) = (f16)(acc[t][rg] + bias);
    }
  }
  __syncthreads();
  if (which < 2) {
    f16* dst = which ? gk : gq;
    for (int idx = threadIdx.x; idx < 64 * C8; idx += 256) {
      int r = idx / C8, c8 = idx % C8;
      int off = ((r * CIN + c8 * 8) * 2) ^ ((r & 7) << 4);
      f16x8 v = *(const f16x8*)((char*)sO + off);
      *(f16x8*)(dst + (R + r) * CIN + c8 * 8) = v;
    }
  } else {
    long img = R >> 14;
    int loc = (int)(R & 16383);
    for (int c = w; c < CIN; c += 4) {
      int off = ((lane * CIN + c) * 2) ^ ((lane & 7) << 4);
      f16 v = *(const f16*)((char*)sO + off);
      gvt[(img * CIN + c) * 16384 + loc + lane] = v;
    }
  }
}

// ---------------- fused window attention, ALL 4 parts + down-conv, single write ----
// Block = one 8x8 window of one (s,b); wave = head. dn accumulated in registers.
template <int CIN, int DH, int CO>
__global__ __launch_bounds__(256) void attn_kernel(
    const f16* __restrict__ gq, const f16* __restrict__ gk,
    const f16* __restrict__ gvt, const f16* __restrict__ wocT,
    const float* __restrict__ fb, float* __restrict__ out, Meta m) {
  constexpr int NKS = DH / 16;
  constexpr int CO4 = CO / 4;
  constexpr int NTC = CO4 / 16;
  constexpr int NKD = CIN / 32;
  constexpr float scale = (DH == 16) ? 0.25f : (DH == 32) ? 0.1767766952966369f
                                                          : 0.1443375672974064f;
  __shared__ f16 P[4 * 64 * 64];
  __shared__ f16 O[64 * CIN];

  int img = blockIdx.y;
  int sidx = img >> 1, b = img & 1;
  int wy = blockIdx.x >> 4, wx = blockIdx.x & 15;
  int h = threadIdx.x >> 6, lane = threadIdx.x & 63;
  int r16 = lane & 15, kq = lane >> 4;
  int fpi = m.pi[sidx], fci = m.ci[sidx], fni = m.ni[sidx];

  int wt[4];
#pragma unroll
  for (int t = 0; t < 4; ++t) {
    int i = t * 16 + r16;
    wt[t] = (wy * 8 + (i >> 3)) * 128 + wx * 8 + (i & 7);
  }

  f32x4 dn[4][NTC] = {};

  for (int p = 0; p < 4; ++p) {
    int qf = (p == 1) ? fpi : ((p == 3) ? fni : fci);
    int kf = (p == 0) ? fpi : ((p == 2) ? fni : fci);
    long qbase = (long)(qf * 2 + b) * 16384;
    int kimg = kf * 2 + b;
    long kbase = (long)kimg * 16384;

    // ---- scores + softmax -> P (wave-private quadrant) ----
    f16x4 bfr[4][NKS];
#pragma unroll
    for (int tj = 0; tj < 4; ++tj)
#pragma unroll
      for (int ks = 0; ks < NKS; ++ks)
        bfr[tj][ks] = *(const f16x4*)(gk + (kbase + wt[tj]) * CIN + h * DH + ks * 16 + kq * 4);

#pragma unroll
    for (int ti = 0; ti < 4; ++ti) {
      f32x4 s4[4] = {};
#pragma unroll
      for (int ks = 0; ks < NKS; ++ks) {
        f16x4 af = *(const f16x4*)(gq + (qbase + wt[ti]) * CIN + h * DH + ks * 16 + kq * 4);
#pragma unroll
        for (int tj = 0; tj < 4; ++tj) s4[tj] = MFMA16(af, bfr[tj][ks], s4[tj]);
      }
#pragma unroll
      for (int rg = 0; rg < 4; ++rg) {
        float mx = fmaxf(fmaxf(s4[0][rg], s4[1][rg]), fmaxf(s4[2][rg], s4[3][rg]));
        mx = fmaxf(mx, __shfl_xor(mx, 1));
        mx = fmaxf(mx, __shfl_xor(mx, 2));
        mx = fmaxf(mx, __shfl_xor(mx, 4));
        mx = fmaxf(mx, __shfl_xor(mx, 8));
        float e[4], sum = 0.f;
#pragma unroll
        for (int tj = 0; tj < 4; ++tj) {
          e[tj] = __expf((s4[tj][rg] - mx) * scale);
          sum += e[tj];
        }
        sum += __shfl_xor(sum, 1);
        sum += __shfl_xor(sum, 2);
        sum += __shfl_xor(sum, 4);
        sum += __shfl_xor(sum, 8);
        float inv = 1.f / sum;
        int i = ti * 16 + kq * 4 + rg;
        int swz = (i & 7) << 3;
#pragma unroll
        for (int tj = 0; tj < 4; ++tj) {
          int off = ((h * 4096 + i * 64 + tj * 16 + r16) * 2) ^ swz;
          *(f16*)((char*)P + off) = (f16)(e[tj] * inv);
        }
      }
    }

    // ---- PV: out_h[64][DH] -> O (swizzled) ----
    f16x4 bv[4][NKS];
#pragma unroll
    for (int ksj = 0; ksj < 4; ++ksj) {
      int jj = ksj * 16 + kq * 4;
      long vloc = (wy * 8 + (jj >> 3)) * 128 + wx * 8 + (jj & 7);
#pragma unroll
      for (int td = 0; td < NKS; ++td) {
        int d = h * DH + td * 16 + r16;
        bv[ksj][td] = *(const f16x4*)(gvt + ((long)kimg * CIN + d) * 16384 + vloc);
      }
    }
#pragma unroll
    for (int ti = 0; ti < 4; ++ti) {
      f32x4 po4[NKS] = {};
#pragma unroll
      for (int ksj = 0; ksj < 4; ++ksj) {
        int i = ti * 16 + r16;
        int off = ((h * 4096 + i * 64 + ksj * 16 + kq * 4) * 2) ^ ((i & 7) << 3);
        f16x4 pa = *(const f16x4*)((char*)P + off);
#pragma unroll
        for (int td = 0; td < NKS; ++td) po4[td] = MFMA16(pa, bv[ksj][td], po4[td]);
      }
#pragma unroll
      for (int td = 0; td < NKS; ++td)
#pragma unroll
        for (int rg = 0; rg < 4; ++rg) {
          int i = ti * 16 + kq * 4 + rg;
          int c = h * DH + td * 16 + r16;
          int off = ((i * CIN + c) * 2) ^ ((i & 7) << 4);
          *(f16*)((char*)O + off) = (f16)po4[td][rg];
        }
    }
    __syncthreads();

    // ---- down: dn += O @ woc_part ----
#pragma unroll
    for (int ks = 0; ks < NKD; ++ks) {
      f16x8 oa[4];
#pragma unroll
      for (int ti = 0; ti < 4; ++ti) {
        int i = ti * 16 + r16;
        int off = ((i * CIN + ks * 32 + kq * 8) * 2) ^ ((i & 7) << 4);
        oa[ti] = *(const f16x8*)((char*)O + off);
      }
#pragma unroll
      for (int tc = 0; tc < NTC; ++tc) {
        int o = h * CO4 + tc * 16 + r16;
        f16x8 bw = *(const f16x8*)(wocT + ((long)o * 4 + p) * CIN + ks * 32 + kq * 8);
#pragma unroll
        for (int ti = 0; ti < 4; ++ti) dn[ti][tc] = MFMA32(oa[ti], bw, dn[ti][tc]);
      }
    }
    __syncthreads();  // before next part overwrites O
  }

  // ---- single fp32 write: relu(dn + fb) ----
#pragma unroll
  for (int ti = 0; ti < 4; ++ti)
#pragma unroll
    for (int rg = 0; rg < 4; ++rg) {
      int i = ti * 16 + kq * 4 + rg;
      long gtok = (long)img * 16384 + (wy * 8 + (i >> 3)) * 128 + wx * 8 + (i & 7);
      float* ar = out + gtok * CO + h * CO4;
#pragma unroll
      for (int tc = 0; tc < NTC; ++tc) {
        int o = tc * 16 + r16;
        ar[o] = fmaxf(dn[ti][tc][rg] + fb[h * CO4 + o], 0.f);
      }
    }
}

extern "C" void kernel_launch(void* const* d_in, const int* in_sizes, int n_in,
                              void* d_out, int out_size, void* d_ws, size_t ws_size,
                              hipStream_t stream) {
  const float* x = (const float*)d_in[0];
#define PRM(l, k) ((const float*)d_in[1 + 9 * (l) + (k)])
  float* outCur = (float*)d_out;                 // [2,128,128,256]
  float* outL1 = (float*)d_out + 8388608;        // [5,2,128,128,128]

  char* ws = (char*)d_ws;
  const size_t OFF_B = 125829120ull;             // qkv arena (max 126 MB @ L1)
  const size_t OFF_W = OFF_B + 75497472ull;      // cur / accum1 arena (75.5 MB)
  f16* qkvbase = (f16*)ws;
  char* wsB = ws + OFF_B;
  float* accum1 = (float*)wsB;
  f16* wqkvT = (f16*)(ws + OFF_W);
  f16* wocT = (f16*)(ws + OFF_W + 262144);
  float* fb = (float*)(ws + OFF_W + 262144 + 524288);

  Meta m0 = {{0, 1, 3, 5, 6}, {1, 2, 4, 6, 7}, {2, 3, 5, 7, 8}};
  Meta m1 = {{0, 1, 2, 0, 0}, {1, 2, 3, 0, 0}, {2, 3, 4, 0, 0}};
  Meta m2 = {{0, 0, 0, 0, 0}, {1, 0, 0, 0, 0}, {2, 0, 0, 0, 0}};
  EmbMap em0 = {{0, 1, 2, 3, 4, 5, 6, 7, 8}};
  EmbMap em1 = {{1, 2, 4, 6, 7, 0, 0, 0, 0}};
  EmbMap em2 = {{2, 4, 6, 0, 0, 0, 0, 0, 0}};

  // ---------------- Level 0: CIN=64, DH=16, CO=128, TL=9, S=5 ----------------
  {
    constexpr int CIN = 64, DH = 16, CO = 128, TL = 9, S = 5;
    long ntok = (long)TL * 2 * 16384;
    f16 *gq = qkvbase, *gk = gq + ntok * CIN, *gvt = gk + ntok * CIN;
    f16* cur = (f16*)wsB;
    ln_kernel<CIN><<<dim3((unsigned)(ntok / 4)), 256, 0, stream>>>(
        x, CIN, PRM(0, 0), PRM(0, 1), PRM(0, 2), cur, CIN, em0);
    wT_kernel<CIN><<<dim3(3 * CIN), 64, 0, stream>>>(PRM(0, 3), wqkvT);
    woc_kernel<CIN, CO><<<dim3(CO), 256, 0, stream>>>(PRM(0, 5), PRM(0, 6), PRM(0, 7), PRM(0, 8), wocT, fb);
    proj_kernel<CIN><<<dim3(3, (unsigned)(ntok / 64)), 256, 0, stream>>>(
        cur, CIN, wqkvT, PRM(0, 4), gq, gk, gvt);
    attn_kernel<CIN, DH, CO><<<dim3(256, S * 2), 256, 0, stream>>>(
        gq, gk, gvt, wocT, fb, outL1, m0);
  }
  // ---------------- Level 1: CIN=128, DH=32, CO=192, TL=5, S=3 ----------------
  {
    constexpr int CIN = 128, DH = 32, CO = 192, TL = 5, S = 3;
    long ntok = (long)TL * 2 * 16384;
    f16 *gq = qkvbase, *gk = gq + ntok * CIN, *gvt = gk + ntok * CIN;
    f16* cur = (f16*)wsB;
    ln_kernel<CIN><<<dim3((unsigned)(ntok / 4)), 256, 0, stream>>>(
        outL1, CIN, PRM(1, 0), PRM(1, 1), PRM(1, 2), cur, CIN, em1);
    wT_kernel<CIN><<<dim3(3 * CIN), 64, 0, stream>>>(PRM(1, 3), wqkvT);
    woc_kernel<CIN, CO><<<dim3(CO), 256, 0, stream>>>(PRM(1, 5), PRM(1, 6), PRM(1, 7), PRM(1, 8), wocT, fb);
    proj_kernel<CIN><<<dim3(3, (unsigned)(ntok / 64)), 256, 0, stream>>>(
        cur, CIN, wqkvT, PRM(1, 4), gq, gk, gvt);
    attn_kernel<CIN, DH, CO><<<dim3(256, S * 2), 256, 0, stream>>>(
        gq, gk, gvt, wocT, fb, accum1, m1);
  }
  // ---------------- Level 2: CIN=192, DH=48, CO=256, TL=3, S=1 ----------------
  {
    constexpr int CIN = 192, DH = 48, CO = 256, TL = 3, S = 1;
    long ntok = (long)TL * 2 * 16384;
    f16 *gq = qkvbase, *gk = gq + ntok * CIN, *gvt = gk + ntok * CIN;
    f16* cur = (f16*)accum1;  // in-place LN: fp32 rows (stride 192) -> f16 (stride 384)
    ln_kernel<CIN><<<dim3((unsigned)(ntok / 4)), 256, 0, stream>>>(
        accum1, CIN, PRM(2, 0), PRM(2, 1), PRM(2, 2), cur, 384, em2);
    wT_kernel<CIN><<<dim3(3 * CIN), 64, 0, stream>>>(PRM(2, 3), wqkvT);
    woc_kernel<CIN, CO><<<dim3(CO), 256, 0, stream>>>(PRM(2, 5), PRM(2, 6), PRM(2, 7), PRM(2, 8), wocT, fb);
    proj_kernel<CIN><<<dim3(3, (unsigned)(ntok / 64)), 256, 0, stream>>>(
        cur, 384, wqkvT, PRM(2, 4), gq, gk, gvt);
    attn_kernel<CIN, DH, CO><<<dim3(256, S * 2), 256, 0, stream>>>(
        gq, gk, gvt, wocT, fb, outCur, m2);
  }
#undef PRM
}

// Round 4
// 905.426 us; speedup vs baseline: 17.9550x; 1.4338x over previous
//
#include <hip/hip_runtime.h>

typedef _Float16 f16;
typedef f16 f16x4 __attribute__((ext_vector_type(4)));
typedef f16 f16x8 __attribute__((ext_vector_type(8)));
typedef float f32x4 __attribute__((ext_vector_type(4)));

#define MFMA16(a, b, c) __builtin_amdgcn_mfma_f32_16x16x16f16((a), (b), (c), 0, 0, 0)
#define MFMA32(a, b, c) __builtin_amdgcn_mfma_f32_16x16x32_f16((a), (b), (c), 0, 0, 0)

struct Meta   { int pi[5], ci[5], ni[5]; };
struct EmbMap { int m[9]; };

// ---------------- LayerNorm(+temporal emb) -> f16, 4 rows/block ----------------
template <int CIN>
__global__ __launch_bounds__(256) void ln_kernel(
    const float* in, long lda, const float* __restrict__ emb,
    const float* __restrict__ lng, const float* __restrict__ lnb,
    f16* out, long ldo, EmbMap em) {
  long row = (long)blockIdx.x * 4 + (threadIdx.x >> 6);
  int t = (int)(row >> 15);  // B*Y*X = 32768
  int lane = threadIdx.x & 63;
  constexpr int NCH = CIN / 64;
  const float* xr = in + row * lda;
  const float* er = emb + (long)em.m[t] * CIN;
  float v[NCH];
  float s = 0.f;
#pragma unroll
  for (int i = 0; i < NCH; ++i) { int c = lane + (i << 6); v[i] = xr[c] + er[c]; s += v[i]; }
#pragma unroll
  for (int o = 32; o >= 1; o >>= 1) s += __shfl_xor(s, o);
  float mu = s * (1.f / CIN), ss = 0.f;
#pragma unroll
  for (int i = 0; i < NCH; ++i) { float d = v[i] - mu; ss += d * d; }
#pragma unroll
  for (int o = 32; o >= 1; o >>= 1) ss += __shfl_xor(ss, o);
  float inv = rsqrtf(ss * (1.f / CIN) + 1e-3f);
  f16* orow = out + row * ldo;
#pragma unroll
  for (int i = 0; i < NCH; ++i) {
    int c = lane + (i << 6);
    orow[c] = (f16)((v[i] - mu) * inv * lng[c] + lnb[c]);
  }
}

// ---------------- wqkv transpose+convert ----------------
template <int CIN>
__global__ __launch_bounds__(64) void wT_kernel(const float* __restrict__ wqkv,
                                                f16* __restrict__ wqkvT) {
  int j = blockIdx.x;
  int which = j / CIN, jj = j % CIN;
  const float* src = wqkv + (long)which * CIN * CIN + jj;
  f16* dst = wqkvT + (long)j * CIN;
  for (int c = threadIdx.x; c < CIN; c += 64) dst[c] = (f16)src[(long)c * CIN];
}

// ---------------- fused out-proj weights ----------------
template <int CIN, int CO>
__global__ __launch_bounds__(256) void woc_kernel(
    const float* __restrict__ wo, const float* __restrict__ bo,
    const float* __restrict__ cw, const float* __restrict__ cb,
    f16* __restrict__ wocT, float* __restrict__ fb) {
  __shared__ float scw[4 * CIN];
  __shared__ float red[256];
  int o = blockIdx.x;
  for (int i = threadIdx.x; i < 4 * CIN; i += 256) scw[i] = cw[(long)i * CO + o];
  __syncthreads();
  for (int pm = threadIdx.x; pm < 4 * CIN; pm += 256) {
    int p = pm / CIN, mm = pm % CIN;
    const float* wr = wo + (long)mm * CIN;
    const float* sc = scw + p * CIN;
    float s = 0.f;
    for (int c = 0; c < CIN; ++c) s += wr[c] * sc[c];
    wocT[(long)o * 4 * CIN + pm] = (f16)s;
  }
  float part = 0.f;
  for (int i = threadIdx.x; i < 4 * CIN; i += 256) part += bo[i % CIN] * scw[i];
  red[threadIdx.x] = part;
  __syncthreads();
  for (int st = 128; st > 0; st >>= 1) {
    if (threadIdx.x < st) red[threadIdx.x] += red[threadIdx.x + st];
    __syncthreads();
  }
  if (threadIdx.x == 0) fb[o] = cb[o] + red[0];
}

// ---------------- QKV projection GEMM -> WINDOW-MAJOR outputs ----------------
// gq/gk: [img*256+win][64][CIN] row-major; gvt: [img*256+win][CIN][64] (V^T).
template <int CIN>
__global__ __launch_bounds__(256) void proj_kernel(
    const f16* __restrict__ cur, long lda, const f16* __restrict__ wT,
    const float* __restrict__ bqkv, f16* __restrict__ gq, f16* __restrict__ gk,
    f16* __restrict__ gvt) {
  constexpr int KS = CIN / 32;
  constexpr int NT = CIN / 16;
  constexpr int C8 = CIN / 8;
  __shared__ f16 sO[64 * CIN];
  int which = blockIdx.x;
  long R = (long)blockIdx.y * 64;
  long img = R >> 14;
  int locbase = (int)(R & 16383);
  int w = threadIdx.x >> 6, lane = threadIdx.x & 63;
  int r16 = lane & 15, kq = lane >> 4;
  const f16* arow = cur + (R + w * 16 + r16) * lda + kq * 8;
  const f16* bbase = wT + ((long)which * CIN + r16) * CIN + kq * 8;
  f32x4 acc[NT] = {};
#pragma unroll
  for (int ks = 0; ks < KS; ++ks) {
    f16x8 a = *(const f16x8*)(arow + ks * 32);
#pragma unroll
    for (int t = 0; t < NT; ++t) {
      f16x8 bb = *(const f16x8*)(bbase + t * 16 * CIN + ks * 32);
      acc[t] = MFMA32(a, bb, acc[t]);
    }
  }
  // stage to LDS (XOR-swizzled rows) with bias
#pragma unroll
  for (int t = 0; t < NT; ++t) {
    float bias = bqkv[which * CIN + t * 16 + r16];
#pragma unroll
    for (int rg = 0; rg < 4; ++rg) {
      int r = w * 16 + kq * 4 + rg;
      int c = t * 16 + r16;
      int off = ((r * CIN + c) * 2) ^ ((r & 7) << 4);
      *(f16*)((char*)sO + off) = (f16)(acc[t][rg] + bias);
    }
  }
  __syncthreads();
  if (which < 2) {
    f16* dst = which ? gk : gq;
    int r = threadIdx.x >> 2;
    int loc = locbase + r;
    int y = loc >> 7, x = loc & 127;
    long grow = (img * 256 + (y >> 3) * 16 + (x >> 3)) * 64 + (y & 7) * 8 + (x & 7);
#pragma unroll
    for (int c8 = threadIdx.x & 3; c8 < C8; c8 += 4) {
      int off = ((r * CIN + c8 * 8) * 2) ^ ((r & 7) << 4);
      f16x8 v = *(const f16x8*)((char*)sO + off);
      *(f16x8*)(dst + grow * CIN + c8 * 8) = v;
    }
  } else {
    int loc = locbase + lane;
    int y = loc >> 7, x = loc & 127;
    long wbase = (img * 256 + (y >> 3) * 16 + (x >> 3));
    int pos = (y & 7) * 8 + (x & 7);
    for (int c = w; c < CIN; c += 4) {
      int off = ((lane * CIN + c) * 2) ^ ((lane & 7) << 4);
      f16 v = *(const f16*)((char*)sO + off);
      gvt[(wbase * CIN + c) * 64 + pos] = v;
    }
  }
}

// ---------------- fused window attention (swapped-MFMA chain) ----------------
// Block = one window of one (s,b); wave = head; all 4 parts, single fp32 write.
// S^T = K*Q^T (P lane-local) -> O^T = V^T*P^T -> dn^T = woc^T*O^T via LDS O.
template <int CIN, int DH, int CO>
__global__ __launch_bounds__(256) void attn_kernel(
    const f16* __restrict__ gq, const f16* __restrict__ gk,
    const f16* __restrict__ gvt, const f16* __restrict__ wocT,
    const float* __restrict__ fb, float* __restrict__ out, Meta m) {
  constexpr int NKS = DH / 16;   // d-tiles per head
  constexpr int CO4 = CO / 4;
  constexpr int NTC = CO4 / 16;  // o-tiles per wave
  constexpr int NKD = CIN / 16;  // down k-tiles
  constexpr float scale = (DH == 16) ? 0.25f : (DH == 32) ? 0.1767766952966369f
                                                          : 0.1443375672974064f;
  __shared__ f16 O[64 * CIN];

  int img = blockIdx.y;
  int sidx = img >> 1, b = img & 1;
  int wid = blockIdx.x;
  int wy = wid >> 4, wx = wid & 15;
  int h = threadIdx.x >> 6, lane = threadIdx.x & 63;
  int r16 = lane & 15, kq = lane >> 4;
  int fpi = m.pi[sidx], fci = m.ci[sidx], fni = m.ni[sidx];

  f32x4 dn[NTC][4] = {};

  for (int p = 0; p < 4; ++p) {
    int qfr = (p == 1) ? fpi : ((p == 3) ? fni : fci);
    int kfr = (p == 0) ? fpi : ((p == 2) ? fni : fci);
    long qwin = (long)((qfr * 2 + b) * 256 + wid);
    long kwin = (long)((kfr * 2 + b) * 256 + wid);

    // ---- S^T = K * Q^T : lane holds S^T[j=tj*16+kq*4+rg][i=ti*16+r16] ----
    f16x4 kf[4][NKS];
#pragma unroll
    for (int tj = 0; tj < 4; ++tj)
#pragma unroll
      for (int ks = 0; ks < NKS; ++ks)
        kf[tj][ks] = *(const f16x4*)(gk + (kwin * 64 + tj * 16 + r16) * CIN +
                                     h * DH + ks * 16 + kq * 4);
    f32x4 sc[4][4] = {};  // [tj][ti]
#pragma unroll
    for (int ti = 0; ti < 4; ++ti) {
      f16x4 qf[NKS];
#pragma unroll
      for (int ks = 0; ks < NKS; ++ks)
        qf[ks] = *(const f16x4*)(gq + (qwin * 64 + ti * 16 + r16) * CIN +
                                 h * DH + ks * 16 + kq * 4);
#pragma unroll
      for (int tj = 0; tj < 4; ++tj)
#pragma unroll
        for (int ks = 0; ks < NKS; ++ks)
          sc[tj][ti] = MFMA16(kf[tj][ks], qf[ks], sc[tj][ti]);
    }

    // ---- softmax over j (16 regs + xor16/32); P stays in registers ----
    f16x4 pa[4][4];  // [tj][ti]
#pragma unroll
    for (int ti = 0; ti < 4; ++ti) {
      float mx = -1e30f;
#pragma unroll
      for (int tj = 0; tj < 4; ++tj)
#pragma unroll
        for (int rg = 0; rg < 4; ++rg) mx = fmaxf(mx, sc[tj][ti][rg]);
      mx = fmaxf(mx, __shfl_xor(mx, 16));
      mx = fmaxf(mx, __shfl_xor(mx, 32));
      float sum = 0.f;
#pragma unroll
      for (int tj = 0; tj < 4; ++tj)
#pragma unroll
        for (int rg = 0; rg < 4; ++rg) {
          float e = __expf((sc[tj][ti][rg] - mx) * scale);
          sc[tj][ti][rg] = e;
          sum += e;
        }
      sum += __shfl_xor(sum, 16);
      sum += __shfl_xor(sum, 32);
      float inv = 1.f / sum;
#pragma unroll
      for (int tj = 0; tj < 4; ++tj) {
        f16x4 pv;
#pragma unroll
        for (int rg = 0; rg < 4; ++rg) pv[rg] = (f16)(sc[tj][ti][rg] * inv);
        pa[tj][ti] = pv;
      }
    }

    // ---- O^T = V^T * P^T -> LDS O[i][c] (XOR-swizzled) ----
#pragma unroll
    for (int dt = 0; dt < NKS; ++dt) {
      f16x4 va[4];
#pragma unroll
      for (int jt = 0; jt < 4; ++jt)
        va[jt] = *(const f16x4*)(gvt + (kwin * CIN + h * DH + dt * 16 + r16) * 64 +
                                 jt * 16 + kq * 4);
#pragma unroll
      for (int ti = 0; ti < 4; ++ti) {
        f32x4 po = {};
#pragma unroll
        for (int jt = 0; jt < 4; ++jt) po = MFMA16(va[jt], pa[jt][ti], po);
        int i = ti * 16 + r16;
        int c0 = h * DH + dt * 16 + kq * 4;
        f16x4 pk;
#pragma unroll
        for (int rg = 0; rg < 4; ++rg) pk[rg] = (f16)po[rg];
        int off = ((i * CIN + c0) * 2) ^ ((i & 7) << 4);
        *(f16x4*)((char*)O + off) = pk;
      }
    }
    __syncthreads();

    // ---- dn^T += woc_p^T * O^T ----
#pragma unroll
    for (int ck = 0; ck < NKD; ++ck) {
      f16x4 ob[4];
#pragma unroll
      for (int ti = 0; ti < 4; ++ti) {
        int i = ti * 16 + r16;
        int off = ((i * CIN + ck * 16 + kq * 4) * 2) ^ ((i & 7) << 4);
        ob[ti] = *(const f16x4*)((char*)O + off);
      }
#pragma unroll
      for (int ot = 0; ot < NTC; ++ot) {
        f16x4 wa = *(const f16x4*)(wocT + ((long)(h * CO4 + ot * 16 + r16)) * 4 * CIN +
                                   p * CIN + ck * 16 + kq * 4);
#pragma unroll
        for (int ti = 0; ti < 4; ++ti) dn[ot][ti] = MFMA16(wa, ob[ti], dn[ot][ti]);
      }
    }
    __syncthreads();  // before next part overwrites O
  }

  // ---- store: relu(dn + fb), packed f32x4 ----
#pragma unroll
  for (int ot = 0; ot < NTC; ++ot) {
    f32x4 fb4 = *(const f32x4*)(fb + h * CO4 + ot * 16 + kq * 4);
#pragma unroll
    for (int ti = 0; ti < 4; ++ti) {
      int i = ti * 16 + r16;
      long gtok = (long)img * 16384 + (wy * 8 + (i >> 3)) * 128 + wx * 8 + (i & 7);
      f32x4 v;
#pragma unroll
      for (int rg = 0; rg < 4; ++rg) v[rg] = fmaxf(dn[ot][ti][rg] + fb4[rg], 0.f);
      *(f32x4*)(out + gtok * CO + h * CO4 + ot * 16 + kq * 4) = v;
    }
  }
}

extern "C" void kernel_launch(void* const* d_in, const int* in_sizes, int n_in,
                              void* d_out, int out_size, void* d_ws, size_t ws_size,
                              hipStream_t stream) {
  const float* x = (const float*)d_in[0];
#define PRM(l, k) ((const float*)d_in[1 + 9 * (l) + (k)])
  float* outCur = (float*)d_out;                 // [2,128,128,256]
  float* outL1 = (float*)d_out + 8388608;        // [5,2,128,128,128]

  char* ws = (char*)d_ws;
  const size_t OFF_B = 125829120ull;             // qkv arena (max 126 MB @ L1)
  const size_t OFF_W = OFF_B + 75497472ull;      // cur / accum1 arena (75.5 MB)
  f16* qkvbase = (f16*)ws;
  char* wsB = ws + OFF_B;
  float* accum1 = (float*)wsB;
  f16* wqkvT = (f16*)(ws + OFF_W);
  f16* wocT = (f16*)(ws + OFF_W + 262144);
  float* fb = (float*)(ws + OFF_W + 262144 + 524288);

  Meta m0 = {{0, 1, 3, 5, 6}, {1, 2, 4, 6, 7}, {2, 3, 5, 7, 8}};
  Meta m1 = {{0, 1, 2, 0, 0}, {1, 2, 3, 0, 0}, {2, 3, 4, 0, 0}};
  Meta m2 = {{0, 0, 0, 0, 0}, {1, 0, 0, 0, 0}, {2, 0, 0, 0, 0}};
  EmbMap em0 = {{0, 1, 2, 3, 4, 5, 6, 7, 8}};
  EmbMap em1 = {{1, 2, 4, 6, 7, 0, 0, 0, 0}};
  EmbMap em2 = {{2, 4, 6, 0, 0, 0, 0, 0, 0}};

  // ---------------- Level 0: CIN=64, DH=16, CO=128, TL=9, S=5 ----------------
  {
    constexpr int CIN = 64, DH = 16, CO = 128, TL = 9, S = 5;
    long ntok = (long)TL * 2 * 16384;
    f16 *gq = qkvbase, *gk = gq + ntok * CIN, *gvt = gk + ntok * CIN;
    f16* cur = (f16*)wsB;
    ln_kernel<CIN><<<dim3((unsigned)(ntok / 4)), 256, 0, stream>>>(
        x, CIN, PRM(0, 0), PRM(0, 1), PRM(0, 2), cur, CIN, em0);
    wT_kernel<CIN><<<dim3(3 * CIN), 64, 0, stream>>>(PRM(0, 3), wqkvT);
    woc_kernel<CIN, CO><<<dim3(CO), 256, 0, stream>>>(PRM(0, 5), PRM(0, 6), PRM(0, 7), PRM(0, 8), wocT, fb);
    proj_kernel<CIN><<<dim3(3, (unsigned)(ntok / 64)), 256, 0, stream>>>(
        cur, CIN, wqkvT, PRM(0, 4), gq, gk, gvt);
    attn_kernel<CIN, DH, CO><<<dim3(256, S * 2), 256, 0, stream>>>(
        gq, gk, gvt, wocT, fb, outL1, m0);
  }
  // ---------------- Level 1: CIN=128, DH=32, CO=192, TL=5, S=3 ----------------
  {
    constexpr int CIN = 128, DH = 32, CO = 192, TL = 5, S = 3;
    long ntok = (long)TL * 2 * 16384;
    f16 *gq = qkvbase, *gk = gq + ntok * CIN, *gvt = gk + ntok * CIN;
    f16* cur = (f16*)wsB;
    ln_kernel<CIN><<<dim3((unsigned)(ntok / 4)), 256, 0, stream>>>(
        outL1, CIN, PRM(1, 0), PRM(1, 1), PRM(1, 2), cur, CIN, em1);
    wT_kernel<CIN><<<dim3(3 * CIN), 64, 0, stream>>>(PRM(1, 3), wqkvT);
    woc_kernel<CIN, CO><<<dim3(CO), 256, 0, stream>>>(PRM(1, 5), PRM(1, 6), PRM(1, 7), PRM(1, 8), wocT, fb);
    proj_kernel<CIN><<<dim3(3, (unsigned)(ntok / 64)), 256, 0, stream>>>(
        cur, CIN, wqkvT, PRM(1, 4), gq, gk, gvt);
    attn_kernel<CIN, DH, CO><<<dim3(256, S * 2), 256, 0, stream>>>(
        gq, gk, gvt, wocT, fb, accum1, m1);
  }
  // ---------------- Level 2: CIN=192, DH=48, CO=256, TL=3, S=1 ----------------
  {
    constexpr int CIN = 192, DH = 48, CO = 256, TL = 3, S = 1;
    long ntok = (long)TL * 2 * 16384;
    f16 *gq = qkvbase, *gk = gq + ntok * CIN, *gvt = gk + ntok * CIN;
    f16* cur = (f16*)accum1;  // in-place LN: fp32 rows (stride 192) -> f16 (stride 384)
    ln_kernel<CIN><<<dim3((unsigned)(ntok / 4)), 256, 0, stream>>>(
        accum1, CIN, PRM(2, 0), PRM(2, 1), PRM(2, 2), cur, 384, em2);
    wT_kernel<CIN><<<dim3(3 * CIN), 64, 0, stream>>>(PRM(2, 3), wqkvT);
    woc_kernel<CIN, CO><<<dim3(CO), 256, 0, stream>>>(PRM(2, 5), PRM(2, 6), PRM(2, 7), PRM(2, 8), wocT, fb);
    proj_kernel<CIN><<<dim3(3, (unsigned)(ntok / 64)), 256, 0, stream>>>(
        cur, 384, wqkvT, PRM(2, 4), gq, gk, gvt);
    attn_kernel<CIN, DH, CO><<<dim3(256, S * 2), 256, 0, stream>>>(
        gq, gk, gvt, wocT, fb, outCur, m2);
  }
#undef PRM
}